// Round 2
// baseline (357.346 us; speedup 1.0000x reference)
//
#include <hip/hip_runtime.h>
#include <hip/hip_bf16.h>
#include <stdint.h>

typedef __attribute__((ext_vector_type(8))) short bf16x8;
typedef __attribute__((ext_vector_type(4))) float f32x4;

#define GLD16(gp, lp) __builtin_amdgcn_global_load_lds( \
    (const __attribute__((address_space(1))) void*)(gp), \
    (__attribute__((address_space(3))) void*)(lp), 16, 0, 0)

// ---------------- convert f32 -> bf16 (x4 vectorized) ----------------
struct bf16_4 { __hip_bfloat16 x, y, z, w; };

__global__ __launch_bounds__(256) void k_conv(const float* __restrict__ in,
                                              __hip_bfloat16* __restrict__ out, int n4)
{
    int i = blockIdx.x * 256 + threadIdx.x;
    if (i >= n4) return;
    float4 v = ((const float4*)in)[i];
    bf16_4 o = { __float2bfloat16(v.x), __float2bfloat16(v.y),
                 __float2bfloat16(v.z), __float2bfloat16(v.w) };
    ((bf16_4*)out)[i] = o;
}

// ------------- transpose+convert: in[R][C] f32 -> out[C][R] bf16 -------------
__global__ __launch_bounds__(256) void k_tconv(const float* __restrict__ in,
                                               __hip_bfloat16* __restrict__ out,
                                               int R, int C)
{
    __shared__ float tile[32][33];
    int c0 = blockIdx.x * 32, r0 = blockIdx.y * 32;
    int tc = threadIdx.x & 31, tr = threadIdx.x >> 5;  // tr in 0..7
#pragma unroll
    for (int i = 0; i < 4; i++)
        tile[tr + i * 8][tc] = in[(size_t)(r0 + tr + i * 8) * C + c0 + tc];
    __syncthreads();
#pragma unroll
    for (int i = 0; i < 4; i++) {
        int r = tr + i * 8;
        out[(size_t)(c0 + r) * R + r0 + tc] = __float2bfloat16(tile[tc][r]);
    }
}

// ---------------- 128x128 bf16 GEMM, C = A @ Bt^T + bias ----------------
// A: [M][K] bf16,  Bt: [N][K] bf16 (i.e. B transposed), bias: [N] f32
// EPI=0: QKV epilogue -> scatter to [3][B*16][S][64] as f32 (outf) + bf16 (outb)
// EPI=1: plain row-major f32 store to outf[M][N]
template <int EPI>
__global__ __launch_bounds__(256) void k_gemm(const __hip_bfloat16* __restrict__ A,
                                              const __hip_bfloat16* __restrict__ Bt,
                                              const float* __restrict__ bias,
                                              float* __restrict__ outf,
                                              __hip_bfloat16* __restrict__ outb,
                                              int M, int N, int K)
{
    __shared__ __hip_bfloat16 As[128 * 32];
    __shared__ __hip_bfloat16 Bs[128 * 32];

    const int tid  = threadIdx.x;
    const int lane = tid & 63, wid = tid >> 6;
    const int wrow = wid >> 1, wcol = wid & 1;
    const int lr = lane & 15, lg = lane >> 4;
    const int m0 = blockIdx.y * 128, n0 = blockIdx.x * 128;

    f32x4 acc[4][4] = {};

    for (int k0 = 0; k0 < K; k0 += 32) {
        __syncthreads();
#pragma unroll
        for (int i = 0; i < 2; i++) {
            int c = i * 256 + tid;
            const __hip_bfloat16* ga = A + (size_t)(m0 + (c >> 2)) * K + k0 + (c & 3) * 8;
            GLD16(ga, As + (size_t)(i * 256 + wid * 64) * 8);
            const __hip_bfloat16* gb = Bt + (size_t)(n0 + (c >> 2)) * K + k0 + (c & 3) * 8;
            GLD16(gb, Bs + (size_t)(i * 256 + wid * 64) * 8);
        }
        __syncthreads();

        bf16x8 af[4], bfr[4];
#pragma unroll
        for (int mi = 0; mi < 4; mi++)
            af[mi] = *(const bf16x8*)(As + (wrow * 64 + mi * 16 + lr) * 32 + 8 * lg);
#pragma unroll
        for (int ni = 0; ni < 4; ni++)
            bfr[ni] = *(const bf16x8*)(Bs + (wcol * 64 + ni * 16 + lr) * 32 + 8 * lg);
#pragma unroll
        for (int mi = 0; mi < 4; mi++)
#pragma unroll
            for (int ni = 0; ni < 4; ni++)
                acc[mi][ni] = __builtin_amdgcn_mfma_f32_16x16x32_bf16(af[mi], bfr[ni], acc[mi][ni], 0, 0, 0);
    }

    // epilogue: lane holds rows 4*lg+j, col lr within each 16x16 frag
#pragma unroll
    for (int mi = 0; mi < 4; mi++) {
#pragma unroll
        for (int ni = 0; ni < 4; ni++) {
#pragma unroll
            for (int j = 0; j < 4; j++) {
                int mg = m0 + wrow * 64 + mi * 16 + 4 * lg + j;
                int ng = n0 + wcol * 64 + ni * 16 + lr;
                float val = acc[mi][ni][j] + bias[ng];
                if (EPI == 0) {
                    int part = ng >> 10;
                    int h    = (ng >> 6) & 15;
                    int dd   = ng & 63;
                    int b    = mg >> 11;
                    int s    = mg & 2047;
                    size_t idx = ((size_t)part << 22) + ((((size_t)b * 16 + h) * 2048 + s) << 6) + dd;
                    outf[idx] = val;
                    outb[idx] = __float2bfloat16(val);
                } else {
                    outf[(size_t)mg * N + ng] = val;
                }
            }
        }
    }
}

// ---------------- flash-style causal attention ----------------
// qkv: [3][32][2048][64] bf16 (part-major), ctx out: [B][S][1024] bf16
__global__ __launch_bounds__(256) void k_attn(const __hip_bfloat16* __restrict__ qkv,
                                              const int* __restrict__ amask,
                                              __hip_bfloat16* __restrict__ ctx)
{
    const int qt = blockIdx.x, bh = blockIdx.y;
    const int b = bh >> 4, h = bh & 15;
    const int lane = threadIdx.x & 63, w = threadIdx.x >> 6;
    const int lr = lane & 15, lg = lane >> 4;
    const int q0 = qt * 64;
    const size_t hb = (size_t)bh * 2048 * 64;
    const __hip_bfloat16* q = qkv + hb;
    const __hip_bfloat16* k = qkv + ((size_t)1 << 22) + hb;
    const __hip_bfloat16* v = qkv + ((size_t)2 << 22) + hb;

    __shared__ __hip_bfloat16 Ks[64 * 64];
    __shared__ __hip_bfloat16 Vt[64 * 72];     // V transposed [d][kv], padded
    __shared__ __hip_bfloat16 Ps[4][16 * 72];  // per-wave P tile
    __shared__ float maskadd[64];

    // Q fragments live in registers for the whole block
    bf16x8 qf[2];
#pragma unroll
    for (int kk = 0; kk < 2; kk++)
        qf[kk] = *(const bf16x8*)(q + (q0 + w * 16 + lr) * 64 + kk * 32 + 8 * lg);

    f32x4 of[4] = {};
    float m_run[4], l_run[4];
#pragma unroll
    for (int j = 0; j < 4; j++) { m_run[j] = -1e30f; l_run[j] = 0.f; }
    const int rowg = q0 + w * 16 + 4 * lg;  // + j gives this lane's rows

    for (int kt = 0; kt <= qt; ++kt) {
        const int k0 = kt * 64;
        __syncthreads();
        // stage K tile (contiguous 8KB) via async global->LDS
#pragma unroll
        for (int i = 0; i < 2; i++) {
            int c = i * 256 + (int)threadIdx.x;
            GLD16(k + k0 * 64 + c * 8, Ks + (size_t)(i * 256 + w * 64) * 8);
        }
        // stage V transposed (scalar LDS writes)
#pragma unroll
        for (int i = 0; i < 2; i++) {
            int c = i * 256 + (int)threadIdx.x;
            bf16x8 vv = *(const bf16x8*)(v + k0 * 64 + c * 8);
            int kv = c >> 3, d0 = (c & 7) * 8;
#pragma unroll
            for (int jj = 0; jj < 8; jj++)
                Vt[(d0 + jj) * 72 + kv] = ((const __hip_bfloat16*)&vv)[jj];
        }
        if (threadIdx.x < 64)
            maskadd[threadIdx.x] = amask[b * 2048 + k0 + (int)threadIdx.x] ? 0.f : -1e30f;
        __syncthreads();

        // S = Q K^T   (each wave: rows w*16..w*16+15, all 64 cols)
        f32x4 sa[4] = {};
#pragma unroll
        for (int ni = 0; ni < 4; ni++)
#pragma unroll
            for (int kk = 0; kk < 2; kk++) {
                bf16x8 kf = *(const bf16x8*)(Ks + (ni * 16 + lr) * 64 + kk * 32 + 8 * lg);
                sa[ni] = __builtin_amdgcn_mfma_f32_16x16x32_bf16(qf[kk], kf, sa[ni], 0, 0, 0);
            }
        // scale + causal + pad mask
#pragma unroll
        for (int ni = 0; ni < 4; ni++) {
            int colg = k0 + ni * 16 + lr;
            float ma = maskadd[ni * 16 + lr];
#pragma unroll
            for (int j = 0; j < 4; j++) {
                float val = sa[ni][j] * 0.125f + ma;
                if (colg > rowg + j) val = -1e30f;
                sa[ni][j] = val;
            }
        }
        // online softmax: row max over 16-lane groups
        float mnew[4], corr[4];
#pragma unroll
        for (int j = 0; j < 4; j++) {
            float t = fmaxf(fmaxf(sa[0][j], sa[1][j]), fmaxf(sa[2][j], sa[3][j]));
            t = fmaxf(t, __shfl_xor(t, 1));
            t = fmaxf(t, __shfl_xor(t, 2));
            t = fmaxf(t, __shfl_xor(t, 4));
            t = fmaxf(t, __shfl_xor(t, 8));
            mnew[j] = fmaxf(m_run[j], t);
            corr[j] = __expf(m_run[j] - mnew[j]);
            m_run[j] = mnew[j];
        }
        float tsum[4] = {0.f, 0.f, 0.f, 0.f};
#pragma unroll
        for (int ni = 0; ni < 4; ni++)
#pragma unroll
            for (int j = 0; j < 4; j++) {
                float p = __expf(sa[ni][j] - mnew[j]);
                sa[ni][j] = p;
                tsum[j] += p;
            }
#pragma unroll
        for (int j = 0; j < 4; j++) {
            float t = tsum[j];
            t += __shfl_xor(t, 1);
            t += __shfl_xor(t, 2);
            t += __shfl_xor(t, 4);
            t += __shfl_xor(t, 8);
            l_run[j] = l_run[j] * corr[j] + t;
#pragma unroll
            for (int nd = 0; nd < 4; nd++) of[nd][j] *= corr[j];
        }
        // P (f32, D-frag layout) -> bf16 via wave-private LDS re-fragmentation
#pragma unroll
        for (int ni = 0; ni < 4; ni++)
#pragma unroll
            for (int j = 0; j < 4; j++)
                Ps[w][(4 * lg + j) * 72 + ni * 16 + lr] = __float2bfloat16(sa[ni][j]);
        asm volatile("s_waitcnt lgkmcnt(0)" ::: "memory");
        __builtin_amdgcn_sched_barrier(0);
        // O += P @ V
#pragma unroll
        for (int kk = 0; kk < 2; kk++) {
            bf16x8 pf = *(const bf16x8*)(&Ps[w][lr * 72 + kk * 32 + 8 * lg]);
#pragma unroll
            for (int nd = 0; nd < 4; nd++) {
                bf16x8 vf = *(const bf16x8*)(Vt + (nd * 16 + lr) * 72 + kk * 32 + 8 * lg);
                of[nd] = __builtin_amdgcn_mfma_f32_16x16x32_bf16(pf, vf, of[nd], 0, 0, 0);
            }
        }
    }
    // epilogue: ctx[b][s][h*64+d] = O / l
#pragma unroll
    for (int j = 0; j < 4; j++) {
        float inv = 1.f / l_run[j];
        int s = rowg + j;
        size_t base = ((size_t)b * 2048 + s) * 1024 + h * 64;
#pragma unroll
        for (int nd = 0; nd < 4; nd++)
            ctx[base + nd * 16 + lr] = __float2bfloat16(of[nd][j] * inv);
    }
}

extern "C" void kernel_launch(void* const* d_in, const int* in_sizes, int n_in,
                              void* d_out, int out_size, void* d_ws, size_t ws_size,
                              hipStream_t stream)
{
    const float* x    = (const float*)d_in[0];
    const int*   am   = (const int*)d_in[1];
    const float* Wqkv = (const float*)d_in[2];
    const float* bqkv = (const float*)d_in[3];
    const float* Wout = (const float*)d_in[4];
    const float* bout = (const float*)d_in[5];
    float* out = (float*)d_out;

    char* ws = (char*)d_ws;
    __hip_bfloat16* x_bf   = (__hip_bfloat16*)(ws);                      //  8 MB
    __hip_bfloat16* Wqkv_t = (__hip_bfloat16*)(ws + ((size_t)8 << 20));  //  6 MB [3072][1024]
    __hip_bfloat16* Wout_t = (__hip_bfloat16*)(ws + ((size_t)14 << 20)); //  2 MB [1024][1024]
    __hip_bfloat16* qkv_bf = (__hip_bfloat16*)(ws + ((size_t)16 << 20)); // 24 MB [3][32][2048][64]
    __hip_bfloat16* ctx_bf = (__hip_bfloat16*)(ws + ((size_t)40 << 20)); //  8 MB [4096][1024]

    // x: 4,194,304 f32 -> bf16
    k_conv<<<4096, 256, 0, stream>>>(x, x_bf, 1048576);
    // W_qkv [1024][3072] -> [3072][1024] bf16
    k_tconv<<<dim3(96, 32), 256, 0, stream>>>(Wqkv, Wqkv_t, 1024, 3072);
    // W_out [1024][1024] -> [1024][1024] bf16 (transposed)
    k_tconv<<<dim3(32, 32), 256, 0, stream>>>(Wout, Wout_t, 1024, 1024);
    // QKV GEMM: [4096x1024] @ [1024x3072]; scatter q,k,v f32 to d_out + bf16 to ws
    k_gemm<0><<<dim3(24, 32), 256, 0, stream>>>(x_bf, Wqkv_t, bqkv,
                                                out + ((size_t)1 << 22), qkv_bf,
                                                4096, 3072, 1024);
    // attention: 32 q-tiles x 32 (b,h) pairs
    k_attn<<<dim3(32, 32), 256, 0, stream>>>(qkv_bf, am, ctx_bf);
    // out-proj GEMM: [4096x1024] @ [1024x1024] -> output (d_out offset 0)
    k_gemm<1><<<dim3(8, 32), 256, 0, stream>>>(ctx_bf, Wout_t, bout,
                                               out, nullptr,
                                               4096, 1024, 1024);
}

// Round 3
// 251.770 us; speedup vs baseline: 1.4193x; 1.4193x over previous
//
#include <hip/hip_runtime.h>
#include <hip/hip_bf16.h>
#include <stdint.h>

typedef __attribute__((ext_vector_type(8))) short bf16x8;
typedef __attribute__((ext_vector_type(4))) float f32x4;

#define GLD16(gp, lp) __builtin_amdgcn_global_load_lds( \
    (const __attribute__((address_space(1))) void*)(gp), \
    (__attribute__((address_space(3))) void*)(lp), 16, 0, 0)

// ---------------- convert f32 -> bf16 (x4 vectorized) ----------------
struct bf16_4 { __hip_bfloat16 x, y, z, w; };

__global__ __launch_bounds__(256) void k_conv(const float* __restrict__ in,
                                              __hip_bfloat16* __restrict__ out, int n4)
{
    int i = blockIdx.x * 256 + threadIdx.x;
    if (i >= n4) return;
    float4 v = ((const float4*)in)[i];
    bf16_4 o = { __float2bfloat16(v.x), __float2bfloat16(v.y),
                 __float2bfloat16(v.z), __float2bfloat16(v.w) };
    ((bf16_4*)out)[i] = o;
}

// ------------- transpose+convert: in[R][C] f32 -> out[C][R] bf16 -------------
__global__ __launch_bounds__(256) void k_tconv(const float* __restrict__ in,
                                               __hip_bfloat16* __restrict__ out,
                                               int R, int C)
{
    __shared__ float tile[32][33];
    int c0 = blockIdx.x * 32, r0 = blockIdx.y * 32;
    int tc = threadIdx.x & 31, tr = threadIdx.x >> 5;  // tr in 0..7
#pragma unroll
    for (int i = 0; i < 4; i++)
        tile[tr + i * 8][tc] = in[(size_t)(r0 + tr + i * 8) * C + c0 + tc];
    __syncthreads();
#pragma unroll
    for (int i = 0; i < 4; i++) {
        int r = tr + i * 8;
        out[(size_t)(c0 + r) * R + r0 + tc] = __float2bfloat16(tile[tc][r]);
    }
}

// ------------- bf16 per-head transpose: vin[32][2048][64] -> vout[32][64][2048] -------------
__global__ __launch_bounds__(256) void k_vtrans(const __hip_bfloat16* __restrict__ vin,
                                                __hip_bfloat16* __restrict__ vout)
{
    __shared__ __hip_bfloat16 t[64 * 80];
    const int kt = blockIdx.x, bh = blockIdx.y;
    const int tid = threadIdx.x;
    const size_t ib = (size_t)bh * 131072;
#pragma unroll
    for (int i = 0; i < 2; i++) {
        int c = i * 256 + tid;
        int kv = c >> 3, d0 = (c & 7) * 8;
        bf16x8 vv = *(const bf16x8*)(vin + ib + (size_t)(kt * 64 + kv) * 64 + d0);
#pragma unroll
        for (int j = 0; j < 8; j++)
            t[(d0 + j) * 80 + kv] = ((const __hip_bfloat16*)&vv)[j];
    }
    __syncthreads();
#pragma unroll
    for (int i = 0; i < 2; i++) {
        int c = i * 256 + tid;
        int d = c >> 3, kv0 = (c & 7) * 8;
        *(bf16x8*)(vout + ib + (size_t)d * 2048 + kt * 64 + kv0) =
            *(const bf16x8*)(t + d * 80 + kv0);
    }
}

// ---------------- 128x128 bf16 GEMM, C = A @ Bt^T + bias ----------------
template <int EPI>
__global__ __launch_bounds__(256) void k_gemm(const __hip_bfloat16* __restrict__ A,
                                              const __hip_bfloat16* __restrict__ Bt,
                                              const float* __restrict__ bias,
                                              float* __restrict__ outf,
                                              __hip_bfloat16* __restrict__ outb,
                                              int M, int N, int K)
{
    __shared__ __hip_bfloat16 As[128 * 32];
    __shared__ __hip_bfloat16 Bs[128 * 32];

    const int tid  = threadIdx.x;
    const int lane = tid & 63, wid = tid >> 6;
    const int wrow = wid >> 1, wcol = wid & 1;
    const int lr = lane & 15, lg = lane >> 4;
    const int m0 = blockIdx.y * 128, n0 = blockIdx.x * 128;

    f32x4 acc[4][4] = {};

    for (int k0 = 0; k0 < K; k0 += 32) {
        __syncthreads();
#pragma unroll
        for (int i = 0; i < 2; i++) {
            int c = i * 256 + tid;
            const __hip_bfloat16* ga = A + (size_t)(m0 + (c >> 2)) * K + k0 + (c & 3) * 8;
            GLD16(ga, As + (size_t)(i * 256 + wid * 64) * 8);
            const __hip_bfloat16* gb = Bt + (size_t)(n0 + (c >> 2)) * K + k0 + (c & 3) * 8;
            GLD16(gb, Bs + (size_t)(i * 256 + wid * 64) * 8);
        }
        __syncthreads();

        bf16x8 af[4], bfr[4];
#pragma unroll
        for (int mi = 0; mi < 4; mi++)
            af[mi] = *(const bf16x8*)(As + (wrow * 64 + mi * 16 + lr) * 32 + 8 * lg);
#pragma unroll
        for (int ni = 0; ni < 4; ni++)
            bfr[ni] = *(const bf16x8*)(Bs + (wcol * 64 + ni * 16 + lr) * 32 + 8 * lg);
#pragma unroll
        for (int mi = 0; mi < 4; mi++)
#pragma unroll
            for (int ni = 0; ni < 4; ni++)
                acc[mi][ni] = __builtin_amdgcn_mfma_f32_16x16x32_bf16(af[mi], bfr[ni], acc[mi][ni], 0, 0, 0);
    }

#pragma unroll
    for (int mi = 0; mi < 4; mi++) {
#pragma unroll
        for (int ni = 0; ni < 4; ni++) {
#pragma unroll
            for (int j = 0; j < 4; j++) {
                int mg = m0 + wrow * 64 + mi * 16 + 4 * lg + j;
                int ng = n0 + wcol * 64 + ni * 16 + lr;
                float val = acc[mi][ni][j] + bias[ng];
                if (EPI == 0) {
                    int part = ng >> 10;
                    int h    = (ng >> 6) & 15;
                    int dd   = ng & 63;
                    int b    = mg >> 11;
                    int s    = mg & 2047;
                    size_t idx = ((size_t)part << 22) + ((((size_t)b * 16 + h) * 2048 + s) << 6) + dd;
                    outf[idx] = val;
                    outb[idx] = __float2bfloat16(val);
                } else {
                    outf[(size_t)mg * N + ng] = val;
                }
            }
        }
    }
}

// ---------------- flash-style causal attention v2 ----------------
// QB=64 (4 waves x 16 rows), KVB=128, paired q-tiles (31-bx, bx): 17 steps/block.
// K tile [128 kv][64 d] and V^T tile [64 d][128 kv] staged via global_load_lds with
// inverse-swizzled per-lane SOURCE + XOR-swizzled READ (rule #21). P tile per-wave,
// XOR-swizzled. All fragment ds_read_b128 are <=2-way bank aliased (free).
__global__ __launch_bounds__(256, 3) void k_attn2(const __hip_bfloat16* __restrict__ qkv,
                                                  const __hip_bfloat16* __restrict__ vT,
                                                  const int* __restrict__ amask,
                                                  __hip_bfloat16* __restrict__ ctx)
{
    const int bx = blockIdx.x;      // 0..15
    const int bh = blockIdx.y;      // 0..31
    const int b = bh >> 4, h = bh & 15;
    const int tid = threadIdx.x;
    const int lane = tid & 63, w = tid >> 6;
    const int lr = lane & 15, lg = lane >> 4;
    const size_t hb = (size_t)bh * (2048 * 64);
    const __hip_bfloat16* qg = qkv + hb;
    const __hip_bfloat16* kg = qkv + ((size_t)1 << 22) + hb;
    const __hip_bfloat16* vt = vT + (size_t)bh * (64 * 2048);

    __shared__ __hip_bfloat16 Ks[128 * 64];     // [kv][d], 8 slots/row, swz s^(r&7)
    __shared__ __hip_bfloat16 Vs[64 * 128];     // [d][kv], 16 slots/row, swz s^(r&15)
    __shared__ __hip_bfloat16 Ps[4][16 * 128];  // per-wave [16 q][128 kv], swz s^row
    __shared__ float maskadd[128];

#pragma unroll 1
    for (int pass = 0; pass < 2; ++pass) {
        const int qt = pass ? bx : (31 - bx);
        const int q0 = qt * 64;
        const int nkt = (64 * qt + 191) >> 7;   // kv tiles covering causal span

        bf16x8 qf[2];
#pragma unroll
        for (int kk = 0; kk < 2; kk++)
            qf[kk] = *(const bf16x8*)(qg + (size_t)(q0 + w * 16 + lr) * 64 + kk * 32 + 8 * lg);

        f32x4 of[4] = {};
        float m_run[4], l_run[4];
#pragma unroll
        for (int j = 0; j < 4; j++) { m_run[j] = -1e30f; l_run[j] = 0.f; }
        const int rowg = q0 + w * 16 + 4 * lg;

#pragma unroll 1
        for (int kt = 0; kt < nkt; ++kt) {
            const int k0 = kt * 128;
            __syncthreads();
            // stage K [128][64]: chunk c -> row r=c>>3, slot sl=c&7; src slot = sl^(r&7)
#pragma unroll
            for (int i = 0; i < 4; i++) {
                int c = i * 256 + tid;
                int r = c >> 3, sl = c & 7;
                GLD16(kg + (size_t)(k0 + r) * 64 + ((sl ^ (r & 7)) * 8),
                      Ks + (size_t)(i * 256 + w * 64) * 8);
            }
            // stage V^T [64][128]: chunk c -> row r=c>>4, slot sl=c&15; src slot = sl^(r&15)
#pragma unroll
            for (int i = 0; i < 4; i++) {
                int c = i * 256 + tid;
                int r = c >> 4, sl = c & 15;
                GLD16(vt + (size_t)r * 2048 + k0 + ((sl ^ (r & 15)) * 8),
                      Vs + (size_t)(i * 256 + w * 64) * 8);
            }
            if (tid < 128) maskadd[tid] = amask[b * 2048 + k0 + tid] ? 0.f : -1e30f;
            __syncthreads();

            // S = Q K^T : 16 MFMA (8 ni x 2 kk)
            f32x4 sa[8] = {};
#pragma unroll
            for (int ni = 0; ni < 8; ni++) {
                int r = ni * 16 + lr;
#pragma unroll
                for (int kk = 0; kk < 2; kk++) {
                    bf16x8 kf = *(const bf16x8*)(Ks + (size_t)r * 64 + (((kk * 4 + lg) ^ (r & 7)) * 8));
                    sa[ni] = __builtin_amdgcn_mfma_f32_16x16x32_bf16(qf[kk], kf, sa[ni], 0, 0, 0);
                }
            }
            // scale + causal + pad mask
#pragma unroll
            for (int ni = 0; ni < 8; ni++) {
                int colg = k0 + ni * 16 + lr;
                float ma = maskadd[ni * 16 + lr];
#pragma unroll
                for (int j = 0; j < 4; j++) {
                    float val = sa[ni][j] * 0.125f + ma;
                    if (colg > rowg + j) val = -1e30f;
                    sa[ni][j] = val;
                }
            }
            // online softmax (rows live in 16-lane groups)
            float mnew[4], corr[4];
#pragma unroll
            for (int j = 0; j < 4; j++) {
                float t = fmaxf(fmaxf(fmaxf(sa[0][j], sa[1][j]), fmaxf(sa[2][j], sa[3][j])),
                                fmaxf(fmaxf(sa[4][j], sa[5][j]), fmaxf(sa[6][j], sa[7][j])));
                t = fmaxf(t, __shfl_xor(t, 1));
                t = fmaxf(t, __shfl_xor(t, 2));
                t = fmaxf(t, __shfl_xor(t, 4));
                t = fmaxf(t, __shfl_xor(t, 8));
                mnew[j] = fmaxf(m_run[j], t);
                corr[j] = __expf(m_run[j] - mnew[j]);
                m_run[j] = mnew[j];
            }
            float tsum[4] = {0.f, 0.f, 0.f, 0.f};
#pragma unroll
            for (int ni = 0; ni < 8; ni++)
#pragma unroll
                for (int j = 0; j < 4; j++) {
                    float p = __expf(sa[ni][j] - mnew[j]);
                    sa[ni][j] = p;
                    tsum[j] += p;
                }
#pragma unroll
            for (int j = 0; j < 4; j++) {
                float t = tsum[j];
                t += __shfl_xor(t, 1);
                t += __shfl_xor(t, 2);
                t += __shfl_xor(t, 4);
                t += __shfl_xor(t, 8);
                l_run[j] = l_run[j] * corr[j] + t;
#pragma unroll
                for (int nd = 0; nd < 4; nd++) of[nd][j] *= corr[j];
            }
            // P -> LDS (bf16, XOR-swizzled), re-fragment for PV
#pragma unroll
            for (int ni = 0; ni < 8; ni++)
#pragma unroll
                for (int j = 0; j < 4; j++) {
                    int row = 4 * lg + j, col = ni * 16 + lr;
                    Ps[w][row * 128 + (((col >> 3) ^ row) * 8) + (col & 7)] =
                        __float2bfloat16(sa[ni][j]);
                }
            asm volatile("s_waitcnt lgkmcnt(0)" ::: "memory");
            __builtin_amdgcn_sched_barrier(0);
            // O += P @ V : 16 MFMA (4 kk x 4 nd)
#pragma unroll
            for (int kk = 0; kk < 4; kk++) {
                bf16x8 pf = *(const bf16x8*)(&Ps[w][lr * 128 + (((kk * 4 + lg) ^ lr) * 8)]);
#pragma unroll
                for (int nd = 0; nd < 4; nd++) {
                    int r = nd * 16 + lr;
                    bf16x8 vf = *(const bf16x8*)(Vs + (size_t)r * 128 + (((kk * 4 + lg) ^ (r & 15)) * 8));
                    of[nd] = __builtin_amdgcn_mfma_f32_16x16x32_bf16(pf, vf, of[nd], 0, 0, 0);
                }
            }
        }
        // epilogue: ctx[b][s][h*64+d] = O / l
#pragma unroll
        for (int j = 0; j < 4; j++) {
            float inv = 1.f / l_run[j];
            int s = rowg + j;
            size_t base = ((size_t)b * 2048 + s) * 1024 + h * 64;
#pragma unroll
            for (int nd = 0; nd < 4; nd++)
                ctx[base + nd * 16 + lr] = __float2bfloat16(of[nd][j] * inv);
        }
    }
}

extern "C" void kernel_launch(void* const* d_in, const int* in_sizes, int n_in,
                              void* d_out, int out_size, void* d_ws, size_t ws_size,
                              hipStream_t stream)
{
    const float* x    = (const float*)d_in[0];
    const int*   am   = (const int*)d_in[1];
    const float* Wqkv = (const float*)d_in[2];
    const float* bqkv = (const float*)d_in[3];
    const float* Wout = (const float*)d_in[4];
    const float* bout = (const float*)d_in[5];
    float* out = (float*)d_out;

    char* ws = (char*)d_ws;
    __hip_bfloat16* x_bf   = (__hip_bfloat16*)(ws);                      //  8 MB (reused as vT after QKV GEMM)
    __hip_bfloat16* Wqkv_t = (__hip_bfloat16*)(ws + ((size_t)8 << 20));  //  6 MB [3072][1024]
    __hip_bfloat16* Wout_t = (__hip_bfloat16*)(ws + ((size_t)14 << 20)); //  2 MB [1024][1024]
    __hip_bfloat16* qkv_bf = (__hip_bfloat16*)(ws + ((size_t)16 << 20)); // 24 MB [3][32][2048][64]
    __hip_bfloat16* ctx_bf = (__hip_bfloat16*)(ws + ((size_t)40 << 20)); //  8 MB [4096][1024]
    __hip_bfloat16* vT     = x_bf;                                       //  8 MB [32][64][2048]

    k_conv<<<4096, 256, 0, stream>>>(x, x_bf, 1048576);
    k_tconv<<<dim3(96, 32), 256, 0, stream>>>(Wqkv, Wqkv_t, 1024, 3072);
    k_tconv<<<dim3(32, 32), 256, 0, stream>>>(Wout, Wout_t, 1024, 1024);
    // QKV GEMM: scatter q,k,v f32 to d_out + bf16 to ws
    k_gemm<0><<<dim3(24, 32), 256, 0, stream>>>(x_bf, Wqkv_t, bqkv,
                                                out + ((size_t)1 << 22), qkv_bf,
                                                4096, 3072, 1024);
    // V^T per head (x_bf is dead now; reuse as vT)
    k_vtrans<<<dim3(32, 32), 256, 0, stream>>>(qkv_bf + ((size_t)2 << 22), vT);
    // attention: 16 paired q-tiles x 32 (b,h)
    k_attn2<<<dim3(16, 32), 256, 0, stream>>>(qkv_bf, vT, am, ctx_bf);
    // out-proj GEMM
    k_gemm<1><<<dim3(8, 32), 256, 0, stream>>>(ctx_bf, Wout_t, bout,
                                               out, nullptr,
                                               4096, 1024, 1024);
}

// Round 5
// 231.614 us; speedup vs baseline: 1.5429x; 1.0870x over previous
//
#include <hip/hip_runtime.h>
#include <hip/hip_bf16.h>
#include <stdint.h>

typedef __attribute__((ext_vector_type(8))) short bf16x8;
typedef __attribute__((ext_vector_type(4))) float f32x4;

#define GLD16(gp, lp) __builtin_amdgcn_global_load_lds( \
    (const __attribute__((address_space(1))) void*)(gp), \
    (__attribute__((address_space(3))) void*)(lp), 16, 0, 0)

// ---------------- convert f32 -> bf16 (x4 vectorized) ----------------
struct bf16_4 { __hip_bfloat16 x, y, z, w; };

__global__ __launch_bounds__(256) void k_conv(const float* __restrict__ in,
                                              __hip_bfloat16* __restrict__ out, int n4)
{
    int i = blockIdx.x * 256 + threadIdx.x;
    if (i >= n4) return;
    float4 v = ((const float4*)in)[i];
    bf16_4 o = { __float2bfloat16(v.x), __float2bfloat16(v.y),
                 __float2bfloat16(v.z), __float2bfloat16(v.w) };
    ((bf16_4*)out)[i] = o;
}

// ------------- transpose+convert: in[R][C] f32 -> out[C][R] bf16 -------------
__global__ __launch_bounds__(256) void k_tconv(const float* __restrict__ in,
                                               __hip_bfloat16* __restrict__ out,
                                               int R, int C)
{
    __shared__ float tile[32][33];
    int c0 = blockIdx.x * 32, r0 = blockIdx.y * 32;
    int tc = threadIdx.x & 31, tr = threadIdx.x >> 5;  // tr in 0..7
#pragma unroll
    for (int i = 0; i < 4; i++)
        tile[tr + i * 8][tc] = in[(size_t)(r0 + tr + i * 8) * C + c0 + tc];
    __syncthreads();
#pragma unroll
    for (int i = 0; i < 4; i++) {
        int r = tr + i * 8;
        out[(size_t)(c0 + r) * R + r0 + tc] = __float2bfloat16(tile[tc][r]);
    }
}

// ------------- bf16 per-head transpose: vin[32][2048][64] -> vout[32][64][2048] -------------
__global__ __launch_bounds__(256) void k_vtrans(const __hip_bfloat16* __restrict__ vin,
                                                __hip_bfloat16* __restrict__ vout)
{
    __shared__ __hip_bfloat16 t[64 * 80];
    const int kt = blockIdx.x, bh = blockIdx.y;
    const int tid = threadIdx.x;
    const size_t ib = (size_t)bh * 131072;
#pragma unroll
    for (int i = 0; i < 2; i++) {
        int c = i * 256 + tid;
        int kv = c >> 3, d0 = (c & 7) * 8;
        bf16x8 vv = *(const bf16x8*)(vin + ib + (size_t)(kt * 64 + kv) * 64 + d0);
#pragma unroll
        for (int j = 0; j < 8; j++)
            t[(d0 + j) * 80 + kv] = ((const __hip_bfloat16*)&vv)[j];
    }
    __syncthreads();
#pragma unroll
    for (int i = 0; i < 2; i++) {
        int c = i * 256 + tid;
        int d = c >> 3, kv0 = (c & 7) * 8;
        *(bf16x8*)(vout + ib + (size_t)d * 2048 + kt * 64 + kv0) =
            *(const bf16x8*)(t + d * 80 + kv0);
    }
}

// ============ big-tile double-buffered GEMM: C = A @ Bt^T + bias ============
// A: [M][K] bf16, Bt: [N][K] bf16. BK=64, dbuf LDS, T2 XOR-swizzle (slot^(row&7)),
// one __syncthreads per K-tile (implicit vmcnt(0) sits a full MFMA block after
// the global_load_lds issues -> latency hidden). TM x TN waves of 64.
// EPI=0: QKV scatter epilogue (f32 to outf + bf16 to outb); EPI=1: row-major f32.
template <int BM, int BN, int TM, int TN, int EPI>
__global__ __launch_bounds__(TM * TN * 64, 2) void k_gemm2(
    const __hip_bfloat16* __restrict__ A,
    const __hip_bfloat16* __restrict__ Bt,
    const float* __restrict__ bias,
    float* __restrict__ outf,
    __hip_bfloat16* __restrict__ outb,
    int M, int N, int K)
{
    constexpr int THREADS = TM * TN * 64;
    constexpr int NMI = BM / TM / 16;   // m-frags per wave
    constexpr int NNI = BN / TN / 16;   // n-frags per wave
    constexpr int ACH = BM * 8 / THREADS;  // A gld issues per thread per K-tile
    constexpr int BCH = BN * 8 / THREADS;

    __shared__ __hip_bfloat16 As[2][BM * 64];
    __shared__ __hip_bfloat16 Bs[2][BN * 64];

    const int tid  = threadIdx.x;
    const int lane = tid & 63, wid = tid >> 6;
    const int wm = wid / TN, wn = wid % TN;
    const int lr = lane & 15, lg = lane >> 4;
    const int m0 = blockIdx.y * BM, n0 = blockIdx.x * BN;
    const int NT = K >> 6;

    f32x4 acc[NMI][NNI] = {};

    // stage K-tile t into buffer bb: linear LDS dest, inverse-swizzled global src
    auto stage = [&](int bb, int t) {
#pragma unroll
        for (int i = 0; i < ACH; i++) {
            int c = i * THREADS + tid;
            int r = c >> 3, sl = c & 7;
            GLD16(A + (size_t)(m0 + r) * K + t * 64 + ((sl ^ (r & 7)) * 8),
                  &As[bb][(size_t)(i * THREADS + wid * 64) * 8]);
        }
#pragma unroll
        for (int i = 0; i < BCH; i++) {
            int c = i * THREADS + tid;
            int r = c >> 3, sl = c & 7;
            GLD16(Bt + (size_t)(n0 + r) * K + t * 64 + ((sl ^ (r & 7)) * 8),
                  &Bs[bb][(size_t)(i * THREADS + wid * 64) * 8]);
        }
    };

    stage(0, 0);
    __syncthreads();           // implicit vmcnt(0): tile 0 landed for all waves
    int cur = 0;
#pragma unroll 1
    for (int t = 0; t < NT; ++t) {
        if (t + 1 < NT) stage(cur ^ 1, t + 1);   // issue early; drained by barrier below
        __builtin_amdgcn_s_setprio(1);
        bf16x8 bfr[NNI][2];
#pragma unroll
        for (int ni = 0; ni < NNI; ni++) {
            int r = wn * (BN / TN) + ni * 16 + lr;
#pragma unroll
            for (int kk = 0; kk < 2; kk++)
                bfr[ni][kk] = *(const bf16x8*)(&Bs[cur][r * 64 + (((kk * 4 + lg) ^ (r & 7)) * 8)]);
        }
#pragma unroll
        for (int mi = 0; mi < NMI; mi++) {
            int r = wm * (BM / TM) + mi * 16 + lr;
            bf16x8 a0 = *(const bf16x8*)(&As[cur][r * 64 + (((0 + lg) ^ (r & 7)) * 8)]);
            bf16x8 a1 = *(const bf16x8*)(&As[cur][r * 64 + (((4 + lg) ^ (r & 7)) * 8)]);
#pragma unroll
            for (int ni = 0; ni < NNI; ni++) {
                acc[mi][ni] = __builtin_amdgcn_mfma_f32_16x16x32_bf16(a0, bfr[ni][0], acc[mi][ni], 0, 0, 0);
                acc[mi][ni] = __builtin_amdgcn_mfma_f32_16x16x32_bf16(a1, bfr[ni][1], acc[mi][ni], 0, 0, 0);
            }
        }
        __builtin_amdgcn_s_setprio(0);
        __syncthreads();       // drains own vmcnt(0) (t+1 loads) + lgkm, publishes
        cur ^= 1;
    }

    // epilogue
#pragma unroll
    for (int mi = 0; mi < NMI; mi++) {
#pragma unroll
        for (int ni = 0; ni < NNI; ni++) {
#pragma unroll
            for (int j = 0; j < 4; j++) {
                int mg = m0 + wm * (BM / TM) + mi * 16 + 4 * lg + j;
                int ng = n0 + wn * (BN / TN) + ni * 16 + lr;
                float val = acc[mi][ni][j] + bias[ng];
                if (EPI == 0) {
                    int part = ng >> 10;
                    int h    = (ng >> 6) & 15;
                    int dd   = ng & 63;
                    int b    = mg >> 11;
                    int s    = mg & 2047;
                    size_t idx = ((size_t)part << 22) + ((((size_t)b * 16 + h) * 2048 + s) << 6) + dd;
                    outf[idx] = val;
                    outb[idx] = __float2bfloat16(val);
                } else {
                    outf[(size_t)mg * N + ng] = val;
                }
            }
        }
    }
}

// ---------------- flash-style causal attention v2 (unchanged from R3) ----------------
__global__ __launch_bounds__(256, 3) void k_attn2(const __hip_bfloat16* __restrict__ qkv,
                                                  const __hip_bfloat16* __restrict__ vT,
                                                  const int* __restrict__ amask,
                                                  __hip_bfloat16* __restrict__ ctx)
{
    const int bx = blockIdx.x;      // 0..15
    const int bh = blockIdx.y;      // 0..31
    const int b = bh >> 4, h = bh & 15;
    const int tid = threadIdx.x;
    const int lane = tid & 63, w = tid >> 6;
    const int lr = lane & 15, lg = lane >> 4;
    const size_t hb = (size_t)bh * (2048 * 64);
    const __hip_bfloat16* qg = qkv + hb;
    const __hip_bfloat16* kg = qkv + ((size_t)1 << 22) + hb;
    const __hip_bfloat16* vt = vT + (size_t)bh * (64 * 2048);

    __shared__ __hip_bfloat16 Ks[128 * 64];     // [kv][d], 8 slots/row, swz s^(r&7)
    __shared__ __hip_bfloat16 Vs[64 * 128];     // [d][kv], 16 slots/row, swz s^(r&15)
    __shared__ __hip_bfloat16 Ps[4][16 * 128];  // per-wave [16 q][128 kv], swz s^row
    __shared__ float maskadd[128];

#pragma unroll 1
    for (int pass = 0; pass < 2; ++pass) {
        const int qt = pass ? bx : (31 - bx);
        const int q0 = qt * 64;
        const int nkt = (64 * qt + 191) >> 7;   // kv tiles covering causal span

        bf16x8 qf[2];
#pragma unroll
        for (int kk = 0; kk < 2; kk++)
            qf[kk] = *(const bf16x8*)(qg + (size_t)(q0 + w * 16 + lr) * 64 + kk * 32 + 8 * lg);

        f32x4 of[4] = {};
        float m_run[4], l_run[4];
#pragma unroll
        for (int j = 0; j < 4; j++) { m_run[j] = -1e30f; l_run[j] = 0.f; }
        const int rowg = q0 + w * 16 + 4 * lg;

#pragma unroll 1
        for (int kt = 0; kt < nkt; ++kt) {
            const int k0 = kt * 128;
            __syncthreads();
#pragma unroll
            for (int i = 0; i < 4; i++) {
                int c = i * 256 + tid;
                int r = c >> 3, sl = c & 7;
                GLD16(kg + (size_t)(k0 + r) * 64 + ((sl ^ (r & 7)) * 8),
                      Ks + (size_t)(i * 256 + w * 64) * 8);
            }
#pragma unroll
            for (int i = 0; i < 4; i++) {
                int c = i * 256 + tid;
                int r = c >> 4, sl = c & 15;
                GLD16(vt + (size_t)r * 2048 + k0 + ((sl ^ (r & 15)) * 8),
                      Vs + (size_t)(i * 256 + w * 64) * 8);
            }
            if (tid < 128) maskadd[tid] = amask[b * 2048 + k0 + tid] ? 0.f : -1e30f;
            __syncthreads();

            // S = Q K^T : 16 MFMA (8 ni x 2 kk)
            f32x4 sa[8] = {};
#pragma unroll
            for (int ni = 0; ni < 8; ni++) {
                int r = ni * 16 + lr;
#pragma unroll
                for (int kk = 0; kk < 2; kk++) {
                    bf16x8 kf = *(const bf16x8*)(Ks + (size_t)r * 64 + (((kk * 4 + lg) ^ (r & 7)) * 8));
                    sa[ni] = __builtin_amdgcn_mfma_f32_16x16x32_bf16(qf[kk], kf, sa[ni], 0, 0, 0);
                }
            }
#pragma unroll
            for (int ni = 0; ni < 8; ni++) {
                int colg = k0 + ni * 16 + lr;
                float ma = maskadd[ni * 16 + lr];
#pragma unroll
                for (int j = 0; j < 4; j++) {
                    float val = sa[ni][j] * 0.125f + ma;
                    if (colg > rowg + j) val = -1e30f;
                    sa[ni][j] = val;
                }
            }
            float mnew[4], corr[4];
#pragma unroll
            for (int j = 0; j < 4; j++) {
                float t = fmaxf(fmaxf(fmaxf(sa[0][j], sa[1][j]), fmaxf(sa[2][j], sa[3][j])),
                                fmaxf(fmaxf(sa[4][j], sa[5][j]), fmaxf(sa[6][j], sa[7][j])));
                t = fmaxf(t, __shfl_xor(t, 1));
                t = fmaxf(t, __shfl_xor(t, 2));
                t = fmaxf(t, __shfl_xor(t, 4));
                t = fmaxf(t, __shfl_xor(t, 8));
                mnew[j] = fmaxf(m_run[j], t);
                corr[j] = __expf(m_run[j] - mnew[j]);
                m_run[j] = mnew[j];
            }
            float tsum[4] = {0.f, 0.f, 0.f, 0.f};
#pragma unroll
            for (int ni = 0; ni < 8; ni++)
#pragma unroll
                for (int j = 0; j < 4; j++) {
                    float p = __expf(sa[ni][j] - mnew[j]);
                    sa[ni][j] = p;
                    tsum[j] += p;
                }
#pragma unroll
            for (int j = 0; j < 4; j++) {
                float t = tsum[j];
                t += __shfl_xor(t, 1);
                t += __shfl_xor(t, 2);
                t += __shfl_xor(t, 4);
                t += __shfl_xor(t, 8);
                l_run[j] = l_run[j] * corr[j] + t;
#pragma unroll
                for (int nd = 0; nd < 4; nd++) of[nd][j] *= corr[j];
            }
#pragma unroll
            for (int ni = 0; ni < 8; ni++)
#pragma unroll
                for (int j = 0; j < 4; j++) {
                    int row = 4 * lg + j, col = ni * 16 + lr;
                    Ps[w][row * 128 + (((col >> 3) ^ row) * 8) + (col & 7)] =
                        __float2bfloat16(sa[ni][j]);
                }
            asm volatile("s_waitcnt lgkmcnt(0)" ::: "memory");
            __builtin_amdgcn_sched_barrier(0);
#pragma unroll
            for (int kk = 0; kk < 4; kk++) {
                bf16x8 pf = *(const bf16x8*)(&Ps[w][lr * 128 + (((kk * 4 + lg) ^ lr) * 8)]);
#pragma unroll
                for (int nd = 0; nd < 4; nd++) {
                    int r = nd * 16 + lr;
                    bf16x8 vf = *(const bf16x8*)(Vs + (size_t)r * 128 + (((kk * 4 + lg) ^ (r & 15)) * 8));
                    of[nd] = __builtin_amdgcn_mfma_f32_16x16x32_bf16(pf, vf, of[nd], 0, 0, 0);
                }
            }
        }
#pragma unroll
        for (int j = 0; j < 4; j++) {
            float inv = 1.f / l_run[j];
            int s = rowg + j;
            size_t base = ((size_t)b * 2048 + s) * 1024 + h * 64;
#pragma unroll
            for (int nd = 0; nd < 4; nd++)
                ctx[base + nd * 16 + lr] = __float2bfloat16(of[nd][j] * inv);
        }
    }
}

extern "C" void kernel_launch(void* const* d_in, const int* in_sizes, int n_in,
                              void* d_out, int out_size, void* d_ws, size_t ws_size,
                              hipStream_t stream)
{
    const float* x    = (const float*)d_in[0];
    const int*   am   = (const int*)d_in[1];
    const float* Wqkv = (const float*)d_in[2];
    const float* bqkv = (const float*)d_in[3];
    const float* Wout = (const float*)d_in[4];
    const float* bout = (const float*)d_in[5];
    float* out = (float*)d_out;

    char* ws = (char*)d_ws;
    __hip_bfloat16* x_bf   = (__hip_bfloat16*)(ws);                      //  8 MB (reused as vT)
    __hip_bfloat16* Wqkv_t = (__hip_bfloat16*)(ws + ((size_t)8 << 20));  //  6 MB [3072][1024]
    __hip_bfloat16* Wout_t = (__hip_bfloat16*)(ws + ((size_t)14 << 20)); //  2 MB [1024][1024]
    __hip_bfloat16* qkv_bf = (__hip_bfloat16*)(ws + ((size_t)16 << 20)); // 24 MB [3][32][2048][64]
    __hip_bfloat16* ctx_bf = (__hip_bfloat16*)(ws + ((size_t)40 << 20)); //  8 MB [4096][1024]
    __hip_bfloat16* vT     = x_bf;

    k_conv<<<4096, 256, 0, stream>>>(x, x_bf, 1048576);
    k_tconv<<<dim3(96, 32), 256, 0, stream>>>(Wqkv, Wqkv_t, 1024, 3072);
    k_tconv<<<dim3(32, 32), 256, 0, stream>>>(Wout, Wout_t, 1024, 1024);
    // QKV GEMM: 256x192 tile, 8 waves, grid 16x16 = 256 blocks (1/CU)
    k_gemm2<256, 192, 2, 4, 0><<<dim3(16, 16), 512, 0, stream>>>(
        x_bf, Wqkv_t, bqkv, out + ((size_t)1 << 22), qkv_bf, 4096, 3072, 1024);
    // V^T per head (x_bf dead now; reuse as vT)
    k_vtrans<<<dim3(32, 32), 256, 0, stream>>>(qkv_bf + ((size_t)2 << 22), vT);
    // attention: 16 paired q-tiles x 32 (b,h)
    k_attn2<<<dim3(16, 32), 256, 0, stream>>>(qkv_bf, vT, am, ctx_bf);
    // out-proj GEMM: 128x128 tile, 4 waves, grid 8x32 = 256 blocks (2/CU)
    k_gemm2<128, 128, 2, 2, 1><<<dim3(8, 32), 256, 0, stream>>>(
        ctx_bf, Wout_t, bout, out, nullptr, 4096, 1024, 1024);
}